// Round 6
// baseline (271.894 us; speedup 1.0000x reference)
//
#include <hip/hip_runtime.h>

#define NB    16
#define NCH   512
#define NCOL  16384
#define NPTS  4096

// Barrier rule for bitonic passes, element mapping i ≡ tid (mod 1024):
//   j >= 1024 : pair is same-thread          -> no barrier
//   j <  64   : partner thread in same wave  -> no barrier (per-wave DS
//               ops are processed in order — HW-validated R3-R5, absmax 0)
//   else      : cross-wave -> __syncthreads(). Conservative lower edge 32.
#define PASS_SYNC(j) do { if ((j) >= 32 && (j) < 1024) __syncthreads(); } while (0)

// ---------------------------------------------------------------------------
// Phase 1a: partial channel-max over half the channels (2-way split for
// occupancy: 2048 waves instead of 1024). pmax layout: [half][b][i].
// ---------------------------------------------------------------------------
__global__ void max_partial_kernel(const float* __restrict__ y,
                                   float* __restrict__ pmax) {
    unsigned t = blockIdx.x * 256u + threadIdx.x;   // 0..4095 per batch
    unsigned b = blockIdx.y;
    unsigned h = blockIdx.z;                        // channel half
    unsigned i = t << 2;
    const float* p = y + ((size_t)b << 23) + ((size_t)h << 22) + i;
    float4 m = *(const float4*)p;
    #pragma unroll 8
    for (int c = 1; c < NCH / 2; ++c) {
        float4 v = *(const float4*)(p + ((size_t)c << 14));
        m.x = fmaxf(m.x, v.x); m.y = fmaxf(m.y, v.y);
        m.z = fmaxf(m.z, v.z); m.w = fmaxf(m.w, v.w);
    }
    *(float4*)(pmax + ((size_t)(h * NB + b) << 14) + i) = m;
}

// ---------------------------------------------------------------------------
// Phase 1b: combine halves, encode 64-bit descending key:
//   key = (sortable_uint(z) << 32) | (16383 - i)   (unique -> total order;
//   desc sort == value desc, index asc == lax.top_k tie-breaking)
// ---------------------------------------------------------------------------
__global__ void key_reduce_kernel(const float* __restrict__ pmax,
                                  unsigned long long* __restrict__ keys) {
    unsigned t = blockIdx.x * 256u + threadIdx.x;
    unsigned b = blockIdx.y;
    unsigned i = t << 2;
    float4 a = *(const float4*)(pmax + ((size_t)b << 14) + i);
    float4 c = *(const float4*)(pmax + ((size_t)(NB + b) << 14) + i);
    float mv[4] = {fmaxf(a.x, c.x), fmaxf(a.y, c.y),
                   fmaxf(a.z, c.z), fmaxf(a.w, c.w)};
    unsigned long long* kp = keys + ((size_t)b << 14) + i;
    #pragma unroll
    for (int q = 0; q < 4; ++q) {
        unsigned u = __float_as_uint(mv[q]);
        unsigned s = (u & 0x80000000u) ? ~u : (u | 0x80000000u);
        kp[q] = ((unsigned long long)s << 32) |
                (unsigned long long)(16383u - (i + q));
    }
}

// ---------------------------------------------------------------------------
// Phase 2a: sort each 2048-chunk descending (bitonic, LDS), in place.
// ---------------------------------------------------------------------------
__global__ __launch_bounds__(1024) void chunk_sort_kernel(
        unsigned long long* __restrict__ keys) {
    __shared__ unsigned long long sk[2048];   // 16 KiB
    unsigned tid = threadIdx.x;
    unsigned b = blockIdx.x >> 3, ch = blockIdx.x & 7;
    unsigned long long* gk = keys + ((size_t)b << 14) + ((size_t)ch << 11);

    sk[tid] = gk[tid];
    sk[tid + 1024] = gk[tid + 1024];
    __syncthreads();
    for (unsigned k = 2; k <= 2048; k <<= 1) {
        for (unsigned j = k >> 1; j > 0; j >>= 1) {
            PASS_SYNC(j);
            #pragma unroll
            for (unsigned s = 0; s < 2; ++s) {
                unsigned i = tid + (s << 10);
                unsigned ixj = i ^ j;
                if (ixj > i) {
                    unsigned long long a = sk[i], c2 = sk[ixj];
                    bool sw = ((i & k) == 0) ? (a < c2) : (a > c2);
                    if (sw) { sk[i] = c2; sk[ixj] = a; }
                }
            }
        }
    }
    __syncthreads();
    gk[tid] = sk[tid];
    gk[tid + 1024] = sk[tid + 1024];
}

// ---------------------------------------------------------------------------
// Phase 2b/c/d: merge-path merge of two sorted-desc lists A,B (length L,
// at src + task*2L and + L), emitting top NPTS of the merge, sorted desc.
// 256 thr/task, 16 outputs/thread: diagonal binary search + serial merge.
// All keys distinct -> strict compares, exact tie order. No barriers.
// ---------------------------------------------------------------------------
__global__ __launch_bounds__(256) void merge_path_kernel(
        const unsigned long long* __restrict__ src,
        unsigned long long* __restrict__ dst,
        int* __restrict__ idx_out, unsigned L) {
    unsigned task = blockIdx.x;
    const unsigned long long* A = src + (size_t)task * (L << 1);
    const unsigned long long* B = A + L;
    unsigned p = threadIdx.x << 4;

    unsigned lo = (p > L) ? (p - L) : 0u;
    unsigned hi = (p < L) ? p : L;
    while (lo < hi) {
        unsigned mid = (lo + hi) >> 1;
        if (A[mid] < B[p - 1 - mid]) hi = mid; else lo = mid + 1;
    }
    unsigned a = lo, b = p - lo;

    unsigned long long av = (a < L) ? A[a] : 0ull;
    unsigned long long bv = (b < L) ? B[b] : 0ull;
    #pragma unroll
    for (unsigned q = 0; q < 16; ++q) {
        bool ta = (b >= L) || (a < L && av > bv);
        unsigned long long o = ta ? av : bv;
        if (ta) { ++a; av = (a < L) ? A[a] : 0ull; }
        else    { ++b; bv = (b < L) ? B[b] : 0ull; }
        if (idx_out)
            idx_out[(size_t)task * NPTS + p + q] =
                (int)(16383u - (unsigned)(o & 0xFFFFFFFFull));
        else
            dst[(size_t)task * NPTS + p + q] = o;
    }
}

// ---------------------------------------------------------------------------
// Phase 3: LDS-staged row gather: 1024 thr + 64 KiB LDS -> 2 blocks/CU.
// Both global sides fully coalesced. rev=1 walks rows in REVERSE of the
// producer (max_partial) read order so the L3-resident tail of y is
// consumed before eviction.
// ---------------------------------------------------------------------------
__global__ __launch_bounds__(1024) void row_gather_kernel(
        const float* __restrict__ src, const int* __restrict__ idx,
        float* __restrict__ out, int nch, int rev) {
    __shared__ float row[NCOL];   // 64 KiB
    unsigned bc = rev ? (gridDim.x - 1u - blockIdx.x) : blockIdx.x;
    unsigned b  = bc / (unsigned)nch;
    const float4* sv = (const float4*)(src + ((size_t)bc << 14));
    float4* rv = (float4*)row;
    #pragma unroll
    for (unsigned i = threadIdx.x; i < NCOL / 4; i += 1024) rv[i] = sv[i];
    __syncthreads();
    const int* ib = idx + (b << 12);
    float* orow = out + (size_t)bc * NPTS;
    unsigned j = threadIdx.x << 2;
    int4 iv = *(const int4*)(ib + j);
    float4 ov;
    ov.x = row[iv.x]; ov.y = row[iv.y];
    ov.z = row[iv.z]; ov.w = row[iv.w];
    *(float4*)(orow + j) = ov;
}

extern "C" void kernel_launch(void* const* d_in, const int* in_sizes, int n_in,
                              void* d_out, int out_size, void* d_ws, size_t ws_size,
                              hipStream_t stream) {
    const float* x = (const float*)d_in[0];
    const float* y = (const float*)d_in[1];
    float* out = (float*)d_out;

    char* ws = (char*)d_ws;
    unsigned long long* keys  = (unsigned long long*)ws;                // 2 MiB
    unsigned long long* keys2 = (unsigned long long*)(ws + (2u << 20)); // 2 MiB
    float* pmax = (float*)(ws + (2u << 20));   // aliases keys2: pmax is dead
                                               // before keys2 is first written
    int* idx = (int*)(ws + (4u << 20));                                 // 256 KiB

    // 1) channel max, 2-way split for occupancy, then key encode
    max_partial_kernel<<<dim3(NCOL / 4 / 256, NB, 2), 256, 0, stream>>>(y, pmax);
    key_reduce_kernel<<<dim3(NCOL / 4 / 256, NB), 256, 0, stream>>>(pmax, keys);
    // 2) sort 2048-chunks descending in place (128 blocks)
    chunk_sort_kernel<<<NB * 8, 1024, 0, stream>>>(keys);
    // 3) merge tree (exact top-4096 truncation per level)
    merge_path_kernel<<<NB * 4, 256, 0, stream>>>(keys, keys2, nullptr, 2048);
    merge_path_kernel<<<NB * 2, 256, 0, stream>>>(keys2, keys, nullptr, 4096);
    merge_path_kernel<<<NB, 256, 0, stream>>>(keys, nullptr, idx, 4096);
    // 4) gathers — y first (big), reverse order for L3 reuse of y's tail
    row_gather_kernel<<<NB * NCH, 1024, 0, stream>>>(
        y, idx, out + (size_t)NB * 3 * NPTS, NCH, 1);
    row_gather_kernel<<<NB * 3, 1024, 0, stream>>>(x, idx, out, 3, 0);
}